// Round 11
// baseline (59.878 us; speedup 1.0000x reference)
//
#include <hip/hip_runtime.h>
#include <hip/hip_bf16.h>
#include <math.h>

#define NB 4
#define NQ 256
#define NK 1024
#define ND 512
#define NA 128

// ws layout (bytes)
#define OFFB_H1 0u          // NB*NQ*NA f32 = 512 KB
#define OFFB_H2 524288u     // NB*NK*NA f32 = 2 MB
#define OFFB_SC 2621440u    // NB*NQ*NK bf16 = 2 MB
#define OFFB_VT 4718592u    // NB*ND*NK bf16 = 4 MB

#define PROJ_BLKS 80        // 5120 rows / 64

typedef __attribute__((ext_vector_type(8))) short short8;
typedef __attribute__((ext_vector_type(8))) unsigned short ushort8_t;
typedef __attribute__((ext_vector_type(4))) float f32x4;
typedef __attribute__((ext_vector_type(2))) float f32x2;

static __device__ __forceinline__ ushort f2bf(float x) {
    __hip_bfloat16 h = __float2bfloat16(x);   // RNE
    return *reinterpret_cast<ushort*>(&h);
}

// LDS address swizzle for k1 MFMA staging (write & read identically).
static __device__ __forceinline__ unsigned swz(int row, int o) {
    return (unsigned)(row * 256 + (o ^ ((row & 7) << 4) ^ (((o >> 7) & 1) << 5)));
}

// ---------------- Kernel 1: fused {MFMA projections | value transpose+cvt}
// blocks 0..79: 64 rows x 128 cols of h = X@W^T + b via bf16 MFMA (fp32 out).
// blocks 80..591: vt[b][d][k] = bf16(value[b][k][d]).
__global__ __launch_bounds__(256) void k_proj_vt(
    const float* __restrict__ query, const float* __restrict__ key,
    const float* __restrict__ value,
    const float* __restrict__ Wq, const float* __restrict__ bq,
    const float* __restrict__ Wk, const float* __restrict__ bk,
    float* __restrict__ h1, float* __restrict__ h2,
    __hip_bfloat16* __restrict__ vt)
{
    __shared__ __align__(16) ushort smem[24576];  // 48KB: Xs 16KB @0, Ws 32KB @16384B
    char* sbytes = (char*)smem;
    const int tid = threadIdx.x;
    const int bid = blockIdx.x;

    if (bid < PROJ_BLKS) {
        const int r0 = bid * 64;
        const bool isQ = r0 < NB * NQ;
        const float* X    = isQ ? query + (size_t)r0 * ND : key + (size_t)(r0 - NB * NQ) * ND;
        const float* W    = isQ ? Wq : Wk;
        const float* bias = isQ ? bq : bk;
        float* hout       = isQ ? h1 + (size_t)r0 * NA : h2 + (size_t)(r0 - NB * NQ) * NA;

        const int wave = tid >> 6, lane = tid & 63;
        const int l15 = lane & 15, lkb = (lane >> 4) * 16;   // k byte-offset in frag

        f32x4 acc[8] = {};

        for (int kc = 0; kc < ND; kc += 128) {
            __syncthreads();
            {   // stage X chunk: 64 rows x 128 k, f32 -> bf16, swizzled
                const int row = tid >> 2, kg = (tid & 3) * 32;
                const float* src = X + (size_t)row * ND + kc + kg;
                #pragma unroll
                for (int j = 0; j < 4; ++j) {
                    const float4 v0 = *(const float4*)(src + j * 8);
                    const float4 v1 = *(const float4*)(src + j * 8 + 4);
                    ushort8_t o;
                    o[0] = f2bf(v0.x); o[1] = f2bf(v0.y); o[2] = f2bf(v0.z); o[3] = f2bf(v0.w);
                    o[4] = f2bf(v1.x); o[5] = f2bf(v1.y); o[6] = f2bf(v1.z); o[7] = f2bf(v1.w);
                    *(ushort8_t*)(sbytes + swz(row, kg * 2 + j * 16)) = o;
                }
            }
            {   // stage W chunk: 128 cols x 128 k, f32 -> bf16, swizzled
                const int row = tid >> 1, kg = (tid & 1) * 64;
                const float* src = W + (size_t)row * ND + kc + kg;
                #pragma unroll
                for (int j = 0; j < 8; ++j) {
                    const float4 v0 = *(const float4*)(src + j * 8);
                    const float4 v1 = *(const float4*)(src + j * 8 + 4);
                    ushort8_t o;
                    o[0] = f2bf(v0.x); o[1] = f2bf(v0.y); o[2] = f2bf(v0.z); o[3] = f2bf(v0.w);
                    o[4] = f2bf(v1.x); o[5] = f2bf(v1.y); o[6] = f2bf(v1.z); o[7] = f2bf(v1.w);
                    *(ushort8_t*)(sbytes + 16384 + swz(row, kg * 2 + j * 16)) = o;
                }
            }
            __syncthreads();
            #pragma unroll
            for (int kk = 0; kk < 4; ++kk) {
                const int arow = wave * 16 + l15;
                const short8 a = *(const short8*)(sbytes + swz(arow, kk * 64 + lkb));
                #pragma unroll
                for (int ct = 0; ct < 8; ++ct) {
                    const int bcol = ct * 16 + l15;
                    const short8 b = *(const short8*)(sbytes + 16384 + swz(bcol, kk * 64 + lkb));
                    acc[ct] = __builtin_amdgcn_mfma_f32_16x16x32_bf16(a, b, acc[ct], 0, 0, 0);
                }
            }
        }

        // epilogue: C/D layout col=lane&15, row=(lane>>4)*4+r (m89-verified)
        const int orow0 = wave * 16 + (lane >> 4) * 4;
        #pragma unroll
        for (int ct = 0; ct < 8; ++ct) {
            const int col = ct * 16 + l15;
            const float bb = bias[col];
            #pragma unroll
            for (int r = 0; r < 4; ++r)
                hout[(size_t)(orow0 + r) * NA + col] = acc[ct][r] + bb;
        }
    } else {
        // value transpose + bf16 convert: 64k x 64d tile
        ushort (*tile)[65] = (ushort (*)[65])smem;
        const int id = bid - PROJ_BLKS;    // 0..511
        const int kt = id & 15;
        const int dt = (id >> 4) & 7;
        const int b  = id >> 7;
        const int k0 = kt * 64, d0 = dt * 64;
        const int tr = tid >> 4, tc4 = (tid & 15) * 4;

        #pragma unroll
        for (int p = 0; p < 4; ++p) {
            const int r = p * 16 + tr;
            const float4 v = *(const float4*)(value + ((size_t)(b * NK + k0 + r)) * ND + d0 + tc4);
            tile[r][tc4 + 0] = f2bf(v.x); tile[r][tc4 + 1] = f2bf(v.y);
            tile[r][tc4 + 2] = f2bf(v.z); tile[r][tc4 + 3] = f2bf(v.w);
        }
        __syncthreads();
        ushort* vo = (ushort*)vt;
        #pragma unroll
        for (int p = 0; p < 4; ++p) {
            const int d = p * 16 + tr;
            ushort4 o;
            o.x = tile[tc4 + 0][d]; o.y = tile[tc4 + 1][d];
            o.z = tile[tc4 + 2][d]; o.w = tile[tc4 + 3][d];
            *(ushort4*)(vo + ((size_t)(b * ND + d0 + d)) * NK + k0 + tc4) = o;
        }
    }
}

// ---------------- Kernel 2: logits + softmax -> score (bf16)
// Same structure as r9 (512 thr, k = tid + 512c, uniform h1/Wa -> scalar pipe),
// but the hot loop is PACKED f32: f32x2 + __builtin_elementwise_{max,fma}
// lower to v_pk_add_f32 / v_pk_max_f32 / v_pk_fma_f32 (VOP3P, 64-bit pairs).
// Halves hot-loop instruction count; tests whether CDNA4 pk-f32 is dual-rate.
__global__ __launch_bounds__(512) void k_logits_softmax(
    const float* __restrict__ h1, const float* __restrict__ h2,
    const float* __restrict__ Wa, __hip_bfloat16* __restrict__ score)
{
    __shared__ float redm[4][8];
    __shared__ float reds[4][8];
    const int tid = threadIdx.x;
    const int b = blockIdx.x >> 6;
    const int q0 = (blockIdx.x & 63) << 2;

    const float4* __restrict__ h2b = (const float4*)(h2 + (size_t)b * NK * NA);
    const float4* __restrict__ h1g = (const float4*)(h1 + (size_t)(b * NQ + q0) * NA);
    const float4* __restrict__ wag = (const float4*)Wa;

    const f32x2 zero = {0.f, 0.f};
    float lg[4][2];
    #pragma unroll
    for (int c = 0; c < 2; ++c) {
        const int k = tid + c * 512;
        const float4* row = h2b + (size_t)k * 32;
        f32x2 s0 = zero, s1 = zero, s2 = zero, s3 = zero;
        #pragma unroll 8
        for (int a4 = 0; a4 < 32; ++a4) {
            const float4 hv = row[a4];         // per-lane (L2)
            const float4 wv = wag[a4];         // wave-uniform -> scalar
            const float4 p0 = h1g[0 * 32 + a4];
            const float4 p1 = h1g[1 * 32 + a4];
            const float4 p2 = h1g[2 * 32 + a4];
            const float4 p3 = h1g[3 * 32 + a4];
            const f32x2 hlo = {hv.x, hv.y}, hhi = {hv.z, hv.w};
            const f32x2 wlo = {wv.x, wv.y}, whi = {wv.z, wv.w};
            {   f32x2 x = (f32x2){p0.x, p0.y} + hlo;
                x = __builtin_elementwise_max(x, zero);
                s0 = __builtin_elementwise_fma(wlo, x, s0);
                x = (f32x2){p0.z, p0.w} + hhi;
                x = __builtin_elementwise_max(x, zero);
                s0 = __builtin_elementwise_fma(whi, x, s0); }
            {   f32x2 x = (f32x2){p1.x, p1.y} + hlo;
                x = __builtin_elementwise_max(x, zero);
                s1 = __builtin_elementwise_fma(wlo, x, s1);
                x = (f32x2){p1.z, p1.w} + hhi;
                x = __builtin_elementwise_max(x, zero);
                s1 = __builtin_elementwise_fma(whi, x, s1); }
            {   f32x2 x = (f32x2){p2.x, p2.y} + hlo;
                x = __builtin_elementwise_max(x, zero);
                s2 = __builtin_elementwise_fma(wlo, x, s2);
                x = (f32x2){p2.z, p2.w} + hhi;
                x = __builtin_elementwise_max(x, zero);
                s2 = __builtin_elementwise_fma(whi, x, s2); }
            {   f32x2 x = (f32x2){p3.x, p3.y} + hlo;
                x = __builtin_elementwise_max(x, zero);
                s3 = __builtin_elementwise_fma(wlo, x, s3);
                x = (f32x2){p3.z, p3.w} + hhi;
                x = __builtin_elementwise_max(x, zero);
                s3 = __builtin_elementwise_fma(whi, x, s3); }
        }
        lg[0][c] = s0[0] + s0[1]; lg[1][c] = s1[0] + s1[1];
        lg[2][c] = s2[0] + s2[1]; lg[3][c] = s3[0] + s3[1];
    }
    // +ba omitted — constant over k, cancels in softmax.

    const int wv_ = tid >> 6, ln = tid & 63;
    float mq[4];
    #pragma unroll
    for (int q = 0; q < 4; ++q) {
        float m = fmaxf(lg[q][0], lg[q][1]);
        for (int off = 32; off > 0; off >>= 1) m = fmaxf(m, __shfl_xor(m, off));
        if (ln == 0) redm[q][wv_] = m;
    }
    __syncthreads();
    #pragma unroll
    for (int q = 0; q < 4; ++q) {
        float m = redm[q][0];
        #pragma unroll
        for (int w = 1; w < 8; ++w) m = fmaxf(m, redm[q][w]);
        mq[q] = m;
    }
    #pragma unroll
    for (int q = 0; q < 4; ++q) {
        float s = 0.f;
        #pragma unroll
        for (int c = 0; c < 2; ++c) { lg[q][c] = __expf(lg[q][c] - mq[q]); s += lg[q][c]; }
        for (int off = 32; off > 0; off >>= 1) s += __shfl_xor(s, off);
        if (ln == 0) reds[q][wv_] = s;
    }
    __syncthreads();
    #pragma unroll
    for (int q = 0; q < 4; ++q) {
        float s = reds[q][0];
        #pragma unroll
        for (int w = 1; w < 8; ++w) s += reds[q][w];
        const float inv = 1.f / s;
        __hip_bfloat16* so = score + (size_t)(b * NQ + q0 + q) * NK + tid;
        #pragma unroll
        for (int c = 0; c < 2; ++c) so[c * 512] = __float2bfloat16(lg[q][c] * inv);
    }
}

// ---------------- Kernel 3: PV via MFMA bf16 [r9-exact]. BM=32/BN=64, 4 waves,
// XCD-aware 1D remap: xcd = bid&7 owns one fixed n-tile -> per-XCD working set
// sc 2MB + vt panel 512KB < 4MB L2 (L3 traffic ~20MB first-touch only).
__global__ __launch_bounds__(256) void k_pv(
    const ushort* __restrict__ sc,   // [B][Q][K] bf16 bits
    const ushort* __restrict__ vt,   // [B][D][K] bf16 bits
    float* __restrict__ out)         // [B][Q][D] f32
{
    const int bid = blockIdx.x;      // 0..255
    const int y   = bid & 7;         // n-tile (one per XCD)
    const int loc = bid >> 3;        // 0..31
    const int x   = loc & 7;         // m-tile
    const int b   = loc >> 3;        // batch

    const int tid = threadIdx.x;
    const int wave = tid >> 6, lane = tid & 63;
    const int wr = wave >> 1, wc = wave & 1;
    const int m0 = x * 32 + wr * 16;
    const int n0 = y * 64 + wc * 32;
    const int l15 = lane & 15, lk = (lane >> 4) * 8;

    const ushort* arow  = sc + (size_t)(b * NQ + m0 + l15) * NK + lk;
    const ushort* b0row = vt + (size_t)(b * ND + n0 + l15) * NK + lk;
    const ushort* b1row = vt + (size_t)(b * ND + n0 + 16 + l15) * NK + lk;

    f32x4 acc0 = {0.f, 0.f, 0.f, 0.f}, acc1 = {0.f, 0.f, 0.f, 0.f};
    #pragma unroll 4
    for (int k = 0; k < NK; k += 32) {
        const short8 a  = *(const short8*)(arow + k);
        const short8 v0 = *(const short8*)(b0row + k);
        const short8 v1 = *(const short8*)(b1row + k);
        acc0 = __builtin_amdgcn_mfma_f32_16x16x32_bf16(a, v0, acc0, 0, 0, 0);
        acc1 = __builtin_amdgcn_mfma_f32_16x16x32_bf16(a, v1, acc1, 0, 0, 0);
    }

    const int orow = (lane >> 4) * 4;
    #pragma unroll
    for (int r = 0; r < 4; ++r) {
        float* po = out + (size_t)(b * NQ + m0 + orow + r) * ND + n0;
        po[l15]      = acc0[r];
        po[16 + l15] = acc1[r];
    }
}

extern "C" void kernel_launch(void* const* d_in, const int* in_sizes, int n_in,
                              void* d_out, int out_size, void* d_ws, size_t ws_size,
                              hipStream_t stream) {
    const float* key   = (const float*)d_in[0];
    const float* query = (const float*)d_in[1];
    const float* value = (const float*)d_in[2];
    const float* Wk    = (const float*)d_in[3];
    const float* bk    = (const float*)d_in[4];
    const float* Wq    = (const float*)d_in[5];
    const float* bq    = (const float*)d_in[6];
    const float* Wa    = (const float*)d_in[7];
    // d_in[8] = ba: cancels in softmax — unused.

    char* ws = (char*)d_ws;
    float* h1 = (float*)(ws + OFFB_H1);
    float* h2 = (float*)(ws + OFFB_H2);
    __hip_bfloat16* sc = (__hip_bfloat16*)(ws + OFFB_SC);
    __hip_bfloat16* vt = (__hip_bfloat16*)(ws + OFFB_VT);

    k_proj_vt<<<PROJ_BLKS + 512, 256, 0, stream>>>(query, key, value, Wq, bq, Wk, bk,
                                                   h1, h2, vt);
    k_logits_softmax<<<256, 512, 0, stream>>>(h1, h2, Wa, sc);
    k_pv<<<256, 256, 0, stream>>>((const ushort*)sc, (const ushort*)vt,
                                  (float*)d_out);
}

// Round 12
// 59.256 us; speedup vs baseline: 1.0105x; 1.0105x over previous
//
#include <hip/hip_runtime.h>
#include <hip/hip_bf16.h>
#include <math.h>

#define NB 4
#define NQ 256
#define NK 1024
#define ND 512
#define NA 128

// ws layout (bytes)
#define OFFB_H1 0u          // NB*NQ*NA f32 = 512 KB
#define OFFB_H2 524288u     // NB*NK*NA f32 = 2 MB
#define OFFB_SC 2621440u    // NB*NQ*NK bf16 = 2 MB
#define OFFB_VT 4718592u    // NB*ND*NK bf16 = 4 MB

#define PROJ_BLKS 80        // 5120 rows / 64

typedef __attribute__((ext_vector_type(8))) short short8;
typedef __attribute__((ext_vector_type(8))) unsigned short ushort8_t;
typedef __attribute__((ext_vector_type(4))) float f32x4;

static __device__ __forceinline__ ushort f2bf(float x) {
    __hip_bfloat16 h = __float2bfloat16(x);   // RNE
    return *reinterpret_cast<ushort*>(&h);
}

// LDS address swizzle for k1 MFMA staging (write & read identically).
static __device__ __forceinline__ unsigned swz(int row, int o) {
    return (unsigned)(row * 256 + (o ^ ((row & 7) << 4) ^ (((o >> 7) & 1) << 5)));
}

// ---------------- Kernel 1: fused {MFMA projections | value transpose+cvt}
// blocks 0..79: 64 rows x 128 cols of h = X@W^T + b via bf16 MFMA (fp32 out).
// blocks 80..591: vt[b][d][k] = bf16(value[b][k][d]).
__global__ __launch_bounds__(256) void k_proj_vt(
    const float* __restrict__ query, const float* __restrict__ key,
    const float* __restrict__ value,
    const float* __restrict__ Wq, const float* __restrict__ bq,
    const float* __restrict__ Wk, const float* __restrict__ bk,
    float* __restrict__ h1, float* __restrict__ h2,
    __hip_bfloat16* __restrict__ vt)
{
    __shared__ __align__(16) ushort smem[24576];  // 48KB: Xs 16KB @0, Ws 32KB @16384B
    char* sbytes = (char*)smem;
    const int tid = threadIdx.x;
    const int bid = blockIdx.x;

    if (bid < PROJ_BLKS) {
        const int r0 = bid * 64;
        const bool isQ = r0 < NB * NQ;
        const float* X    = isQ ? query + (size_t)r0 * ND : key + (size_t)(r0 - NB * NQ) * ND;
        const float* W    = isQ ? Wq : Wk;
        const float* bias = isQ ? bq : bk;
        float* hout       = isQ ? h1 + (size_t)r0 * NA : h2 + (size_t)(r0 - NB * NQ) * NA;

        const int wave = tid >> 6, lane = tid & 63;
        const int l15 = lane & 15, lkb = (lane >> 4) * 16;   // k byte-offset in frag

        f32x4 acc[8] = {};

        for (int kc = 0; kc < ND; kc += 128) {
            __syncthreads();
            {   // stage X chunk: 64 rows x 128 k, f32 -> bf16, swizzled
                const int row = tid >> 2, kg = (tid & 3) * 32;
                const float* src = X + (size_t)row * ND + kc + kg;
                #pragma unroll
                for (int j = 0; j < 4; ++j) {
                    const float4 v0 = *(const float4*)(src + j * 8);
                    const float4 v1 = *(const float4*)(src + j * 8 + 4);
                    ushort8_t o;
                    o[0] = f2bf(v0.x); o[1] = f2bf(v0.y); o[2] = f2bf(v0.z); o[3] = f2bf(v0.w);
                    o[4] = f2bf(v1.x); o[5] = f2bf(v1.y); o[6] = f2bf(v1.z); o[7] = f2bf(v1.w);
                    *(ushort8_t*)(sbytes + swz(row, kg * 2 + j * 16)) = o;
                }
            }
            {   // stage W chunk: 128 cols x 128 k, f32 -> bf16, swizzled
                const int row = tid >> 1, kg = (tid & 1) * 64;
                const float* src = W + (size_t)row * ND + kc + kg;
                #pragma unroll
                for (int j = 0; j < 8; ++j) {
                    const float4 v0 = *(const float4*)(src + j * 8);
                    const float4 v1 = *(const float4*)(src + j * 8 + 4);
                    ushort8_t o;
                    o[0] = f2bf(v0.x); o[1] = f2bf(v0.y); o[2] = f2bf(v0.z); o[3] = f2bf(v0.w);
                    o[4] = f2bf(v1.x); o[5] = f2bf(v1.y); o[6] = f2bf(v1.z); o[7] = f2bf(v1.w);
                    *(ushort8_t*)(sbytes + 16384 + swz(row, kg * 2 + j * 16)) = o;
                }
            }
            __syncthreads();
            #pragma unroll
            for (int kk = 0; kk < 4; ++kk) {
                const int arow = wave * 16 + l15;
                const short8 a = *(const short8*)(sbytes + swz(arow, kk * 64 + lkb));
                #pragma unroll
                for (int ct = 0; ct < 8; ++ct) {
                    const int bcol = ct * 16 + l15;
                    const short8 b = *(const short8*)(sbytes + 16384 + swz(bcol, kk * 64 + lkb));
                    acc[ct] = __builtin_amdgcn_mfma_f32_16x16x32_bf16(a, b, acc[ct], 0, 0, 0);
                }
            }
        }

        // epilogue: C/D layout col=lane&15, row=(lane>>4)*4+r (m89-verified)
        const int orow0 = wave * 16 + (lane >> 4) * 4;
        #pragma unroll
        for (int ct = 0; ct < 8; ++ct) {
            const int col = ct * 16 + l15;
            const float bb = bias[col];
            #pragma unroll
            for (int r = 0; r < 4; ++r)
                hout[(size_t)(orow0 + r) * NA + col] = acc[ct][r] + bb;
        }
    } else {
        // value transpose + bf16 convert: 64k x 64d tile
        ushort (*tile)[65] = (ushort (*)[65])smem;
        const int id = bid - PROJ_BLKS;    // 0..511
        const int kt = id & 15;
        const int dt = (id >> 4) & 7;
        const int b  = id >> 7;
        const int k0 = kt * 64, d0 = dt * 64;
        const int tr = tid >> 4, tc4 = (tid & 15) * 4;

        #pragma unroll
        for (int p = 0; p < 4; ++p) {
            const int r = p * 16 + tr;
            const float4 v = *(const float4*)(value + ((size_t)(b * NK + k0 + r)) * ND + d0 + tc4);
            tile[r][tc4 + 0] = f2bf(v.x); tile[r][tc4 + 1] = f2bf(v.y);
            tile[r][tc4 + 2] = f2bf(v.z); tile[r][tc4 + 3] = f2bf(v.w);
        }
        __syncthreads();
        ushort* vo = (ushort*)vt;
        #pragma unroll
        for (int p = 0; p < 4; ++p) {
            const int d = p * 16 + tr;
            ushort4 o;
            o.x = tile[tc4 + 0][d]; o.y = tile[tc4 + 1][d];
            o.z = tile[tc4 + 2][d]; o.w = tile[tc4 + 3][d];
            *(ushort4*)(vo + ((size_t)(b * ND + d0 + d)) * NK + k0 + tc4) = o;
        }
    }
}

// ---------------- Kernel 2: logits + softmax -> score (bf16)  [r9-exact]
// block = (b, 4 q-rows), 512 threads. Thread handles k = tid + 512c (c=0..1).
// h1/Wa reads are wave-uniform -> scalar-pipe loads; only per-lane h2 remains.
// r11 measured: pk-f32 VOP3P rewrite is NOT faster (59.9 vs 58.2) — the fp32
// pipe is FLOP-limited, not issue-limited. Scalar form is the floor.
__global__ __launch_bounds__(512) void k_logits_softmax(
    const float* __restrict__ h1, const float* __restrict__ h2,
    const float* __restrict__ Wa, __hip_bfloat16* __restrict__ score)
{
    __shared__ float redm[4][8];
    __shared__ float reds[4][8];
    const int tid = threadIdx.x;
    const int b = blockIdx.x >> 6;
    const int q0 = (blockIdx.x & 63) << 2;

    const float4* __restrict__ h2b = (const float4*)(h2 + (size_t)b * NK * NA);
    const float4* __restrict__ h1g = (const float4*)(h1 + (size_t)(b * NQ + q0) * NA);
    const float4* __restrict__ wag = (const float4*)Wa;

    float lg[4][2];
    #pragma unroll
    for (int c = 0; c < 2; ++c) {
        const int k = tid + c * 512;
        const float4* row = h2b + (size_t)k * 32;
        float s0 = 0.f, s1 = 0.f, s2 = 0.f, s3 = 0.f;
        #pragma unroll 8
        for (int a4 = 0; a4 < 32; ++a4) {
            const float4 hv = row[a4];         // per-lane (L2)
            const float4 wv = wag[a4];         // wave-uniform -> scalar
            const float4 p0 = h1g[0 * 32 + a4];
            const float4 p1 = h1g[1 * 32 + a4];
            const float4 p2 = h1g[2 * 32 + a4];
            const float4 p3 = h1g[3 * 32 + a4];
            s0 = fmaf(wv.x, fmaxf(p0.x + hv.x, 0.f), s0);
            s0 = fmaf(wv.y, fmaxf(p0.y + hv.y, 0.f), s0);
            s0 = fmaf(wv.z, fmaxf(p0.z + hv.z, 0.f), s0);
            s0 = fmaf(wv.w, fmaxf(p0.w + hv.w, 0.f), s0);
            s1 = fmaf(wv.x, fmaxf(p1.x + hv.x, 0.f), s1);
            s1 = fmaf(wv.y, fmaxf(p1.y + hv.y, 0.f), s1);
            s1 = fmaf(wv.z, fmaxf(p1.z + hv.z, 0.f), s1);
            s1 = fmaf(wv.w, fmaxf(p1.w + hv.w, 0.f), s1);
            s2 = fmaf(wv.x, fmaxf(p2.x + hv.x, 0.f), s2);
            s2 = fmaf(wv.y, fmaxf(p2.y + hv.y, 0.f), s2);
            s2 = fmaf(wv.z, fmaxf(p2.z + hv.z, 0.f), s2);
            s2 = fmaf(wv.w, fmaxf(p2.w + hv.w, 0.f), s2);
            s3 = fmaf(wv.x, fmaxf(p3.x + hv.x, 0.f), s3);
            s3 = fmaf(wv.y, fmaxf(p3.y + hv.y, 0.f), s3);
            s3 = fmaf(wv.z, fmaxf(p3.z + hv.z, 0.f), s3);
            s3 = fmaf(wv.w, fmaxf(p3.w + hv.w, 0.f), s3);
        }
        lg[0][c] = s0; lg[1][c] = s1; lg[2][c] = s2; lg[3][c] = s3;
    }
    // +ba omitted — constant over k, cancels in softmax.

    const int wv_ = tid >> 6, ln = tid & 63;
    float mq[4];
    #pragma unroll
    for (int q = 0; q < 4; ++q) {
        float m = fmaxf(lg[q][0], lg[q][1]);
        for (int off = 32; off > 0; off >>= 1) m = fmaxf(m, __shfl_xor(m, off));
        if (ln == 0) redm[q][wv_] = m;
    }
    __syncthreads();
    #pragma unroll
    for (int q = 0; q < 4; ++q) {
        float m = redm[q][0];
        #pragma unroll
        for (int w = 1; w < 8; ++w) m = fmaxf(m, redm[q][w]);
        mq[q] = m;
    }
    #pragma unroll
    for (int q = 0; q < 4; ++q) {
        float s = 0.f;
        #pragma unroll
        for (int c = 0; c < 2; ++c) { lg[q][c] = __expf(lg[q][c] - mq[q]); s += lg[q][c]; }
        for (int off = 32; off > 0; off >>= 1) s += __shfl_xor(s, off);
        if (ln == 0) reds[q][wv_] = s;
    }
    __syncthreads();
    #pragma unroll
    for (int q = 0; q < 4; ++q) {
        float s = reds[q][0];
        #pragma unroll
        for (int w = 1; w < 8; ++w) s += reds[q][w];
        const float inv = 1.f / s;
        __hip_bfloat16* so = score + (size_t)(b * NQ + q0 + q) * NK + tid;
        #pragma unroll
        for (int c = 0; c < 2; ++c) so[c * 512] = __float2bfloat16(lg[q][c] * inv);
    }
}

// ---------------- Kernel 3: PV via MFMA bf16 [r9-exact]. BM=32/BN=64, 4 waves,
// XCD-aware 1D remap: xcd = bid&7 owns one fixed n-tile -> per-XCD working set
// sc 2MB + vt panel 512KB < 4MB L2 (L3 traffic ~20MB first-touch only).
__global__ __launch_bounds__(256) void k_pv(
    const ushort* __restrict__ sc,   // [B][Q][K] bf16 bits
    const ushort* __restrict__ vt,   // [B][D][K] bf16 bits
    float* __restrict__ out)         // [B][Q][D] f32
{
    const int bid = blockIdx.x;      // 0..255
    const int y   = bid & 7;         // n-tile (one per XCD)
    const int loc = bid >> 3;        // 0..31
    const int x   = loc & 7;         // m-tile
    const int b   = loc >> 3;        // batch

    const int tid = threadIdx.x;
    const int wave = tid >> 6, lane = tid & 63;
    const int wr = wave >> 1, wc = wave & 1;
    const int m0 = x * 32 + wr * 16;
    const int n0 = y * 64 + wc * 32;
    const int l15 = lane & 15, lk = (lane >> 4) * 8;

    const ushort* arow  = sc + (size_t)(b * NQ + m0 + l15) * NK + lk;
    const ushort* b0row = vt + (size_t)(b * ND + n0 + l15) * NK + lk;
    const ushort* b1row = vt + (size_t)(b * ND + n0 + 16 + l15) * NK + lk;

    f32x4 acc0 = {0.f, 0.f, 0.f, 0.f}, acc1 = {0.f, 0.f, 0.f, 0.f};
    #pragma unroll 4
    for (int k = 0; k < NK; k += 32) {
        const short8 a  = *(const short8*)(arow + k);
        const short8 v0 = *(const short8*)(b0row + k);
        const short8 v1 = *(const short8*)(b1row + k);
        acc0 = __builtin_amdgcn_mfma_f32_16x16x32_bf16(a, v0, acc0, 0, 0, 0);
        acc1 = __builtin_amdgcn_mfma_f32_16x16x32_bf16(a, v1, acc1, 0, 0, 0);
    }

    const int orow = (lane >> 4) * 4;
    #pragma unroll
    for (int r = 0; r < 4; ++r) {
        float* po = out + (size_t)(b * NQ + m0 + orow + r) * ND + n0;
        po[l15]      = acc0[r];
        po[16 + l15] = acc1[r];
    }
}

extern "C" void kernel_launch(void* const* d_in, const int* in_sizes, int n_in,
                              void* d_out, int out_size, void* d_ws, size_t ws_size,
                              hipStream_t stream) {
    const float* key   = (const float*)d_in[0];
    const float* query = (const float*)d_in[1];
    const float* value = (const float*)d_in[2];
    const float* Wk    = (const float*)d_in[3];
    const float* bk    = (const float*)d_in[4];
    const float* Wq    = (const float*)d_in[5];
    const float* bq    = (const float*)d_in[6];
    const float* Wa    = (const float*)d_in[7];
    // d_in[8] = ba: cancels in softmax — unused.

    char* ws = (char*)d_ws;
    float* h1 = (float*)(ws + OFFB_H1);
    float* h2 = (float*)(ws + OFFB_H2);
    __hip_bfloat16* sc = (__hip_bfloat16*)(ws + OFFB_SC);
    __hip_bfloat16* vt = (__hip_bfloat16*)(ws + OFFB_VT);

    k_proj_vt<<<PROJ_BLKS + 512, 256, 0, stream>>>(query, key, value, Wq, bq, Wk, bk,
                                                   h1, h2, vt);
    k_logits_softmax<<<256, 512, 0, stream>>>(h1, h2, Wa, sc);
    k_pv<<<256, 256, 0, stream>>>((const ushort*)sc, (const ushort*)vt,
                                  (float*)d_out);
}